// Round 5
// baseline (1888.125 us; speedup 1.0000x reference)
//
#include <hip/hip_runtime.h>
#include <hip/hip_fp16.h>
#include <math.h>

#define NA 100000
#define NB 100000
#define NROW 100000   // all four relations have 100000 output rows
#define FT 128
#define H1 128
#define H2 64
#define OUTD 64

#define RBITS 8
#define NBUK  ((NROW + 255) >> 8)     // 391 buckets of 256 rows
#define BCAP  4992                    // staging capacity per bucket
#define CHUNK 4096                    // edges per binA block

typedef __attribute__((ext_vector_type(8))) _Float16 f16x8;
typedef __attribute__((ext_vector_type(4))) float f32x4;

// ---------------- zero fill (small int arrays) ----------------
__global__ __launch_bounds__(256) void zero_k(float4* __restrict__ p, int n4) {
    int i = blockIdx.x * 256 + threadIdx.x;
    if (i < n4) p[i] = make_float4(0.f, 0.f, 0.f, 0.f);
}

// ---------------- weight convert: f32 row-major [K][N] -> fp16 col-major [N][K]
struct WJob { const float* src; int K; int N; int dstoff; };
struct WJobs { WJob j[12]; };
__global__ __launch_bounds__(256) void cvtw_k(WJobs jb, __half* __restrict__ dst) {
    const WJob w = jb.j[blockIdx.x];
    const int KN = w.K * w.N;
    __half* d = dst + w.dstoff;
    for (int i = threadIdx.x; i < KN; i += 256) {
        const int k = i / w.N, n = i - k * w.N;
        d[n * w.K + k] = (__half)w.src[i];
    }
}

// ---------------- CSR build phase A: LDS bucket binning ----------------
__global__ __launch_bounds__(256) void binA_k(
    const int* __restrict__ rows, const int* __restrict__ cols,
    const float* __restrict__ vals, int* __restrict__ gcur,
    int2* __restrict__ stag, int E)
{
    __shared__ int lcnt[NBUK];
    __shared__ int lcnt2[NBUK];
    __shared__ int loff[NBUK + 1];
    __shared__ int gb[NBUK];
    __shared__ int2 sbuf[CHUNK];
    __shared__ int wsum[4];

    const int t = threadIdx.x;
    const int base = blockIdx.x * CHUNK;
    const int n = min(CHUNK, E - base);

    for (int i = t; i < NBUK; i += 256) { lcnt[i] = 0; lcnt2[i] = 0; }
    __syncthreads();

    for (int i = t; i < n; i += 256)
        atomicAdd(&lcnt[rows[base + i] >> RBITS], 1);
    __syncthreads();

    {
        const int i0 = 2 * t, i1 = 2 * t + 1;
        int a = (i0 < NBUK) ? lcnt[i0] : 0;
        int b = (i1 < NBUK) ? lcnt[i1] : 0;
        int s = a + b;
        int inc = s;
#pragma unroll
        for (int m = 1; m < 64; m <<= 1) {
            int u = __shfl_up(inc, m);
            if ((t & 63) >= m) inc += u;
        }
        if ((t & 63) == 63) wsum[t >> 6] = inc;
        __syncthreads();
        int woff = 0;
        const int w = t >> 6;
        for (int i = 0; i < 4; i++) if (i < w) woff += wsum[i];
        const int ex = inc - s + woff;
        if (i0 <= NBUK) loff[i0] = ex;
        if (i1 <= NBUK) loff[i1] = ex + a;
    }
    __syncthreads();

    for (int b = t; b < NBUK; b += 256) {
        const int c = lcnt[b];
        gb[b] = c ? atomicAdd(&gcur[b], c) : 0;
    }
    __syncthreads();

    for (int i = t; i < n; i += 256) {
        const int r = rows[base + i];
        const int c = cols[base + i];
        const float v = vals[base + i];
        const int b = r >> RBITS;
        const int rank = atomicAdd(&lcnt2[b], 1);
        sbuf[loff[b] + rank] = make_int2(c | ((r & 255) << 17), __float_as_int(v));
    }
    __syncthreads();

    for (int s = t; s < n; s += 256) {
        int lo = 0, hi = NBUK - 1;
        while (lo < hi) {
            const int mid = (lo + hi + 1) >> 1;
            if (loff[mid] <= s) lo = mid; else hi = mid - 1;
        }
        const int idx = gb[lo] + (s - loff[lo]);
        if (idx < BCAP) stag[(size_t)lo * BCAP + idx] = sbuf[s];
    }
}

// ---------------- CSR build: scan bucket totals (1 block per relation) ------
__global__ __launch_bounds__(256) void scanb_k(const int* __restrict__ gcur4,
                                               int* __restrict__ gbase4,
                                               int* __restrict__ rp4)
{
    __shared__ int wsum[4];
    const int rel = blockIdx.x;
    const int* gc = gcur4 + rel * NBUK;
    int* gbase = gbase4 + rel * (NBUK + 1);
    const int t = threadIdx.x;
    const int i0 = 2 * t, i1 = 2 * t + 1;
    int a = (i0 < NBUK) ? gc[i0] : 0;
    int b = (i1 < NBUK) ? gc[i1] : 0;
    int s = a + b;
    int inc = s;
#pragma unroll
    for (int m = 1; m < 64; m <<= 1) {
        int u = __shfl_up(inc, m);
        if ((t & 63) >= m) inc += u;
    }
    if ((t & 63) == 63) wsum[t >> 6] = inc;
    __syncthreads();
    int woff = 0;
    const int w = t >> 6;
    for (int i = 0; i < 4; i++) if (i < w) woff += wsum[i];
    const int ex = inc - s + woff;
    if (i0 <= NBUK) gbase[i0] = ex;
    if (i1 <= NBUK) gbase[i1] = ex + a;
    if (t == 255) rp4[(size_t)rel * (NROW + 1) + NROW] = ex + s;
}

// ---------------- CSR build phase B: per-bucket place + rp ----------------
__global__ __launch_bounds__(256) void placeB_k(
    const int* __restrict__ gcur, const int* __restrict__ gbase,
    const int2* __restrict__ stag, int2* __restrict__ edgesS,
    int* __restrict__ rp, int Nrow)
{
    __shared__ int hist[256];
    __shared__ int hoff[256];
    __shared__ int hcur[256];
    __shared__ int2 obuf[BCAP];
    __shared__ int wsum[4];

    const int b = blockIdx.x;
    const int t = threadIdx.x;
    const int n = min(gcur[b], BCAP);
    const int2* src = stag + (size_t)b * BCAP;
    const int fbase = gbase[b];

    hist[t] = 0; hcur[t] = 0;
    __syncthreads();
    for (int s = t; s < n; s += 256)
        atomicAdd(&hist[(src[s].x >> 17) & 255], 1);
    __syncthreads();
    {
        const int a = hist[t];
        int inc = a;
#pragma unroll
        for (int m = 1; m < 64; m <<= 1) {
            int u = __shfl_up(inc, m);
            if ((t & 63) >= m) inc += u;
        }
        if ((t & 63) == 63) wsum[t >> 6] = inc;
        __syncthreads();
        int woff = 0;
        const int w = t >> 6;
        for (int i = 0; i < 4; i++) if (i < w) woff += wsum[i];
        hoff[t] = inc - a + woff;
    }
    __syncthreads();
    const int row = (b << RBITS) + t;
    if (row < Nrow) rp[row] = fbase + hoff[t];
    for (int s = t; s < n; s += 256) {
        const int2 ev = src[s];
        const int rloc = (ev.x >> 17) & 255;
        const int rank = atomicAdd(&hcur[rloc], 1);
        obuf[hoff[rloc] + rank] = make_int2(ev.x & 0x1FFFF, ev.y);
    }
    __syncthreads();
    for (int s = t; s < n; s += 256)
        edgesS[fbase + s] = obuf[s];
}

// ---------------- fused SpMM + GCN act + semantic attention ----------------
// One wave per output row. Gathers both relations into registers, computes
// both attention scores in-register (select-fold shuffle reduction), applies
// softmax blend, writes e directly. No LDS, no g0/g1 round-trip.

__device__ __forceinline__ float lrelu(float x) { return x > 0.f ? x : 0.01f * x; }

// reduce 32 per-lane partials q[j] across 64 lanes; returns s_{lane&31}
__device__ __forceinline__ float fold32(float q[32], int lane) {
#pragma unroll
    for (int i = 0; i < 32; i++) q[i] += __shfl_xor(q[i], 32);
    float v16[16];
#pragma unroll
    for (int i = 0; i < 16; i++) {
        const bool hi = (lane & 16);
        float keep = hi ? q[i + 16] : q[i];
        float send = hi ? q[i] : q[i + 16];
        v16[i] = keep + __shfl_xor(send, 16);
    }
    float v8[8];
#pragma unroll
    for (int i = 0; i < 8; i++) {
        const bool hi = (lane & 8);
        float keep = hi ? v16[i + 8] : v16[i];
        float send = hi ? v16[i] : v16[i + 8];
        v8[i] = keep + __shfl_xor(send, 8);
    }
    float v4[4];
#pragma unroll
    for (int i = 0; i < 4; i++) {
        const bool hi = (lane & 4);
        float keep = hi ? v8[i + 4] : v8[i];
        float send = hi ? v8[i] : v8[i + 4];
        v4[i] = keep + __shfl_xor(send, 4);
    }
    float v2[2];
#pragma unroll
    for (int i = 0; i < 2; i++) {
        const bool hi = (lane & 2);
        float keep = hi ? v4[i + 2] : v4[i];
        float send = hi ? v4[i] : v4[i + 2];
        v2[i] = keep + __shfl_xor(send, 2);
    }
    {
        const bool hi = (lane & 1);
        float keep = hi ? v2[1] : v2[0];
        float send = hi ? v2[0] : v2[1];
        return keep + __shfl_xor(send, 1);
    }
}

// reduce 16 per-lane partials across 64 lanes; returns s_{lane&15}
__device__ __forceinline__ float fold16(float q[16], int lane) {
#pragma unroll
    for (int i = 0; i < 16; i++) q[i] += __shfl_xor(q[i], 32);
#pragma unroll
    for (int i = 0; i < 16; i++) q[i] += __shfl_xor(q[i], 16);
    float v8[8];
#pragma unroll
    for (int i = 0; i < 8; i++) {
        const bool hi = (lane & 8);
        float keep = hi ? q[i + 8] : q[i];
        float send = hi ? q[i] : q[i + 8];
        v8[i] = keep + __shfl_xor(send, 8);
    }
    float v4[4];
#pragma unroll
    for (int i = 0; i < 4; i++) {
        const bool hi = (lane & 4);
        float keep = hi ? v8[i + 4] : v8[i];
        float send = hi ? v8[i] : v8[i + 4];
        v4[i] = keep + __shfl_xor(send, 4);
    }
    float v2[2];
#pragma unroll
    for (int i = 0; i < 2; i++) {
        const bool hi = (lane & 2);
        float keep = hi ? v4[i + 2] : v4[i];
        float send = hi ? v4[i] : v4[i + 2];
        v2[i] = keep + __shfl_xor(send, 2);
    }
    {
        const bool hi = (lane & 1);
        float keep = hi ? v2[1] : v2[0];
        float send = hi ? v2[0] : v2[1];
        return keep + __shfl_xor(send, 1);
    }
}

// attention score w = sum_j tanh(s_j + b1_j) * W2_j for one relation (F=128)
__device__ __forceinline__ float score128(float hx, float hy, int lane,
                                          const float* __restrict__ W1,
                                          const float* __restrict__ b1,
                                          const float* __restrict__ W2) {
    const float4* w1r0 = (const float4*)(W1 + (size_t)(2 * lane) * 32);
    const float4* w1r1 = (const float4*)(W1 + (size_t)(2 * lane + 1) * 32);
    float q[32];
#pragma unroll
    for (int c = 0; c < 8; c++) {
        const float4 a = w1r0[c];
        const float4 b = w1r1[c];
        q[4 * c + 0] = hx * a.x + hy * b.x;
        q[4 * c + 1] = hx * a.y + hy * b.y;
        q[4 * c + 2] = hx * a.z + hy * b.z;
        q[4 * c + 3] = hx * a.w + hy * b.w;
    }
    const float s = fold32(q, lane);
    const int j = lane & 31;
    float t = tanhf(s + b1[j]) * W2[j];
#pragma unroll
    for (int d = 1; d <= 16; d <<= 1) t += __shfl_xor(t, d);
    return t;
}

// attention score for F=64 (H=16)
__device__ __forceinline__ float score64(float h, int lane,
                                         const float* __restrict__ W1,
                                         const float* __restrict__ b1,
                                         const float* __restrict__ W2) {
    const float4* w1r = (const float4*)(W1 + (size_t)lane * 16);
    float q[16];
#pragma unroll
    for (int c = 0; c < 4; c++) {
        const float4 a = w1r[c];
        q[4 * c + 0] = h * a.x;
        q[4 * c + 1] = h * a.y;
        q[4 * c + 2] = h * a.z;
        q[4 * c + 3] = h * a.w;
    }
    const float s = fold16(q, lane);
    const int j = lane & 15;
    float t = tanhf(s + b1[j]) * W2[j];
#pragma unroll
    for (int d = 1; d <= 8; d <<= 1) t += __shfl_xor(t, d);
    return t;
}

template<int F>
__device__ __forceinline__ float2 gatherF(const int* __restrict__ rp,
                                          const int2* __restrict__ edges,
                                          const __half* __restrict__ X,
                                          int row, int lane) {
    const int s = rp[row];
    const int e = rp[row + 1];
    float ax = 0.f, ay = 0.f;
    if constexpr (F == 128) {
        const __half2* Xl = (const __half2*)X + lane;
        int j = s;
        for (; j + 3 < e; j += 4) {
            int2 e0 = edges[j], e1 = edges[j+1], e2 = edges[j+2], e3 = edges[j+3];
            float2 x0 = __half22float2(Xl[(size_t)e0.x * 64]);
            float2 x1 = __half22float2(Xl[(size_t)e1.x * 64]);
            float2 x2 = __half22float2(Xl[(size_t)e2.x * 64]);
            float2 x3 = __half22float2(Xl[(size_t)e3.x * 64]);
            const float v0 = __int_as_float(e0.y), v1 = __int_as_float(e1.y);
            const float v2 = __int_as_float(e2.y), v3 = __int_as_float(e3.y);
            ax += v0 * x0.x + v1 * x1.x + v2 * x2.x + v3 * x3.x;
            ay += v0 * x0.y + v1 * x1.y + v2 * x2.y + v3 * x3.y;
        }
        for (; j < e; j++) {
            int2 ev = edges[j];
            float2 x = __half22float2(Xl[(size_t)ev.x * 64]);
            const float v = __int_as_float(ev.y);
            ax += v * x.x; ay += v * x.y;
        }
    } else {
        const __half* Xl = X + lane;
        int j = s;
        for (; j + 3 < e; j += 4) {
            int2 e0 = edges[j], e1 = edges[j+1], e2 = edges[j+2], e3 = edges[j+3];
            float x0 = __half2float(Xl[(size_t)e0.x * 64]);
            float x1 = __half2float(Xl[(size_t)e1.x * 64]);
            float x2 = __half2float(Xl[(size_t)e2.x * 64]);
            float x3 = __half2float(Xl[(size_t)e3.x * 64]);
            ax += __int_as_float(e0.y) * x0 + __int_as_float(e1.y) * x1
                + __int_as_float(e2.y) * x2 + __int_as_float(e3.y) * x3;
        }
        for (; j < e; j++) {
            int2 ev = edges[j];
            ax += __int_as_float(ev.y) * __half2float(Xl[(size_t)ev.x * 64]);
        }
    }
    return make_float2(ax, ay);
}

template<int F>
__global__ __launch_bounds__(256) void fspmm_att_k(
    const int* __restrict__ rp0, const int2* __restrict__ ed0,
    const __half* __restrict__ X0, const float* __restrict__ bias0,
    const int* __restrict__ rp1, const int2* __restrict__ ed1,
    const __half* __restrict__ X1, const float* __restrict__ bias1,
    const float* __restrict__ W1, const float* __restrict__ b1,
    const float* __restrict__ W2, float* __restrict__ out, int N)
{
    const int wid  = (blockIdx.x * 256 + threadIdx.x) >> 6;
    const int lane = threadIdx.x & 63;
    if (wid >= N) return;

    const float2 a0 = gatherF<F>(rp0, ed0, X0, wid, lane);
    const float2 a1 = gatherF<F>(rp1, ed1, X1, wid, lane);

    float h0x, h0y = 0.f, h1x, h1y = 0.f;
    float w0, w1;
    if constexpr (F == 128) {
        const float2 b0v = *(const float2*)(bias0 + 2 * lane);
        const float2 b1v = *(const float2*)(bias1 + 2 * lane);
        h0x = lrelu(a0.x + b0v.x); h0y = lrelu(a0.y + b0v.y);
        h1x = lrelu(a1.x + b1v.x); h1y = lrelu(a1.y + b1v.y);
        w0 = score128(h0x, h0y, lane, W1, b1, W2);
        w1 = score128(h1x, h1y, lane, W1, b1, W2);
    } else {
        h0x = lrelu(a0.x + bias0[lane]);
        h1x = lrelu(a1.x + bias1[lane]);
        w0 = score64(h0x, lane, W1, b1, W2);
        w1 = score64(h1x, lane, W1, b1, W2);
    }

    const float mx = fmaxf(w0, w1);
    const float e0 = expf(w0 - mx), e1 = expf(w1 - mx);
    const float inv = 1.f / (e0 + e1);
    const float be0 = e0 * inv, be1 = e1 * inv;

    if constexpr (F == 128) {
        float2 o = make_float2(be0 * h0x + be1 * h1x, be0 * h0y + be1 * h1y);
        *(float2*)(out + (size_t)wid * F + 2 * lane) = o;
    } else {
        out[(size_t)wid * F + lane] = be0 * h0x + be1 * h1x;
    }
}

// ---------------- MFMA GEMM: C = A@W [+bias] [+C], optional fp16 out -------
template<int K, int BN, bool BIAS, bool ACCUM, bool HOUT>
__global__ __launch_bounds__(256) void mgemm_k(
    const float* __restrict__ A,
    const __half* __restrict__ Wt,
    const float* __restrict__ bias,
    float* __restrict__ C, int M)
{
    constexpr int BM = (BN == 128) ? 128 : 256;
    constexpr int WN = BN / 64;          // waves along N
    const int t = threadIdx.x;
    const int wid = t >> 6;
    const int lane = t & 63;
    const int wr = wid / WN;
    const int wc = wid - wr * WN;
    const int row0 = blockIdx.x * BM + wr * 64;
    const int col0 = wc * 64;
    const int lrow = lane & 15;
    const int kg = lane >> 4;

    f32x4 acc[4][4];
#pragma unroll
    for (int i = 0; i < 4; i++)
#pragma unroll
        for (int j = 0; j < 4; j++) acc[i][j] = (f32x4){0.f, 0.f, 0.f, 0.f};

    const float* ap[4];
#pragma unroll
    for (int i = 0; i < 4; i++) {
        int r = row0 + i * 16 + lrow;
        r = r < M ? r : M - 1;           // clamp: loads valid, store masked
        ap[i] = A + (size_t)r * K + kg * 8;
    }
    const __half* bp[4];
#pragma unroll
    for (int j = 0; j < 4; j++)
        bp[j] = Wt + (size_t)(col0 + j * 16 + lrow) * K + kg * 8;

#pragma unroll
    for (int k0 = 0; k0 < K; k0 += 32) {
        f16x8 af[4], bf[4];
#pragma unroll
        for (int i = 0; i < 4; i++) {
            const f32x4 lo = *(const f32x4*)(ap[i] + k0);
            const f32x4 hi = *(const f32x4*)(ap[i] + k0 + 4);
            f16x8 v;
            v[0] = (_Float16)lo.x; v[1] = (_Float16)lo.y;
            v[2] = (_Float16)lo.z; v[3] = (_Float16)lo.w;
            v[4] = (_Float16)hi.x; v[5] = (_Float16)hi.y;
            v[6] = (_Float16)hi.z; v[7] = (_Float16)hi.w;
            af[i] = v;
        }
#pragma unroll
        for (int j = 0; j < 4; j++)
            bf[j] = *(const f16x8*)(bp[j] + k0);
#pragma unroll
        for (int i = 0; i < 4; i++)
#pragma unroll
            for (int j = 0; j < 4; j++)
                acc[i][j] = __builtin_amdgcn_mfma_f32_16x16x32_f16(af[i], bf[j], acc[i][j], 0, 0, 0);
    }

#pragma unroll
    for (int i = 0; i < 4; i++) {
#pragma unroll
        for (int r = 0; r < 4; r++) {
            const int row = row0 + i * 16 + kg * 4 + r;
            if (row < M) {
#pragma unroll
                for (int j = 0; j < 4; j++) {
                    const int col = col0 + j * 16 + lrow;
                    float v = acc[i][j][r];
                    if (BIAS) v += bias[col];
                    if (HOUT) {
                        ((__half*)C)[(size_t)row * BN + col] = (__half)v;
                    } else {
                        float* cp = C + (size_t)row * BN + col;
                        if (ACCUM) v += *cp;
                        *cp = v;
                    }
                }
            }
        }
    }
}

// ---------------- launch ----------------
extern "C" void kernel_launch(void* const* d_in, const int* in_sizes, int n_in,
                              void* d_out, int out_size, void* d_ws, size_t ws_size,
                              hipStream_t stream)
{
    const float* feat = (const float*)d_in[0];
    const int*   row_aa = (const int*)d_in[1];
    const int*   col_aa = (const int*)d_in[2];
    const float* val_aa = (const float*)d_in[3];
    const int*   row_ab = (const int*)d_in[4];
    const int*   col_ab = (const int*)d_in[5];
    const float* val_ab = (const float*)d_in[6];
    const int*   row_ba = (const int*)d_in[7];
    const int*   col_ba = (const int*)d_in[8];
    const float* val_ba = (const float*)d_in[9];
    const int*   row_bb = (const int*)d_in[10];
    const int*   col_bb = (const int*)d_in[11];
    const float* val_bb = (const float*)d_in[12];
    const float* W0_aa = (const float*)d_in[13]; const float* b0_aa = (const float*)d_in[14];
    const float* W1_aa = (const float*)d_in[15]; const float* b1_aa = (const float*)d_in[16];
    const float* W0_ab = (const float*)d_in[17]; const float* b0_ab = (const float*)d_in[18];
    const float* W1_ab = (const float*)d_in[19]; const float* b1_ab = (const float*)d_in[20];
    const float* W0_ba = (const float*)d_in[21]; const float* b0_ba = (const float*)d_in[22];
    const float* W1_ba = (const float*)d_in[23]; const float* b1_ba = (const float*)d_in[24];
    const float* W0_bb = (const float*)d_in[25]; const float* b0_bb = (const float*)d_in[26];
    const float* W1_bb = (const float*)d_in[27]; const float* b1_bb = (const float*)d_in[28];
    const float* att0_a_W1 = (const float*)d_in[29];
    const float* att0_a_b1 = (const float*)d_in[30];
    const float* att0_a_W2 = (const float*)d_in[31];
    const float* att1_a_W1 = (const float*)d_in[32];
    const float* att1_a_b1 = (const float*)d_in[33];
    const float* att1_a_W2 = (const float*)d_in[34];
    const float* Wf_a = (const float*)d_in[35]; const float* bf_a = (const float*)d_in[36];
    const float* att0_b_W1 = (const float*)d_in[37];
    const float* att0_b_b1 = (const float*)d_in[38];
    const float* att0_b_W2 = (const float*)d_in[39];
    const float* att1_b_W1 = (const float*)d_in[40];
    const float* att1_b_b1 = (const float*)d_in[41];
    const float* att1_b_W2 = (const float*)d_in[42];
    const float* Wf_b = (const float*)d_in[43]; const float* bf_b = (const float*)d_in[44];

    const int E_r[4] = { in_sizes[1], in_sizes[4], in_sizes[7], in_sizes[10] };
    const int* rows_r[4] = { row_aa, row_ab, row_ba, row_bb };
    const int* cols_r[4] = { col_aa, col_ab, col_ba, col_bb };
    const float* vals_r[4] = { val_aa, val_ab, val_ba, val_bb };

    const size_t RSZ = (size_t)12800000;
    size_t Etot = (size_t)E_r[0] + E_r[1] + E_r[2] + E_r[3];
    size_t need = (3 * RSZ + (size_t)4 * (NROW + 1) + (size_t)4 * NBUK
                   + (size_t)4 * (NBUK + 1) + 2 * Etot + 61456 + 64) * 4;
    if (ws_size < need) return;

    float* ws = (float*)d_ws;
    float* A0 = ws;
    float* A1 = ws + RSZ;
    float* A2 = ws + 2 * RSZ;
    float* A3 = (float*)d_out;            // e1_b lives here until final projection
    int*   rp4    = (int*)(ws + 3 * RSZ);
    int*   gcur4  = rp4 + (size_t)4 * (NROW + 1);
    int*   gbase4 = gcur4 + (size_t)4 * NBUK;
    int2*  edgesS = (int2*)(gbase4 + (size_t)4 * (NBUK + 1));
    __half* wtH   = (__half*)((int*)edgesS + 2 * Etot);   // 122880 halves, 16B-aligned
    int2*  stag   = (int2*)ws;            // staging overlaps A0/A1 (unused during build)

    size_t eoff[4];
    eoff[0] = 0; eoff[1] = eoff[0] + E_r[0];
    eoff[2] = eoff[1] + E_r[1]; eoff[3] = eoff[2] + E_r[2];

    float* out = (float*)d_out;
    const float* fa = feat;
    const float* fb = feat + (size_t)NA * FT;

    const dim3 blk(256);
    const int gM128 = (NROW + 127) / 128;      // mgemm BN=128 grid
    const int gM256 = (NROW + 255) / 256;      // mgemm BN=64 grid
    const int spg = (NROW * 64 + 255) / 256;   // fused: one wave per row

    // fp16 col-major weight offsets (halves)
    const int o0aa = 0,      o0ab = 16384, o0ba = 32768, o0bb = 49152;
    const int o1aa = 65536,  o1ab = 73728, o1ba = 81920, o1bb = 90112;
    const int ofau = 98304,  ofaf = 102400, ofbu = 110592, ofbf = 114688;

    // ================= weight conversion + CSR build =================
    zero_k<<<(NBUK + 255) / 256, blk, 0, stream>>>((float4*)gcur4, NBUK);  // 4*NBUK ints
    {
        WJobs jb;
        jb.j[0]  = { W0_aa, 128, 128, o0aa };
        jb.j[1]  = { W0_ab, 128, 128, o0ab };
        jb.j[2]  = { W0_ba, 128, 128, o0ba };
        jb.j[3]  = { W0_bb, 128, 128, o0bb };
        jb.j[4]  = { W1_aa, 128, 64,  o1aa };
        jb.j[5]  = { W1_ab, 128, 64,  o1ab };
        jb.j[6]  = { W1_ba, 128, 64,  o1ba };
        jb.j[7]  = { W1_bb, 128, 64,  o1bb };
        jb.j[8]  = { Wf_a,            64,  64, ofau };
        jb.j[9]  = { Wf_a + 64 * 64,  128, 64, ofaf };
        jb.j[10] = { Wf_b,            64,  64, ofbu };
        jb.j[11] = { Wf_b + 64 * 64,  128, 64, ofbf };
        cvtw_k<<<12, blk, 0, stream>>>(jb, wtH);
    }
    for (int r = 0; r < 4; r++)
        binA_k<<<(E_r[r] + CHUNK - 1) / CHUNK, blk, 0, stream>>>(
            rows_r[r], cols_r[r], vals_r[r], gcur4 + (size_t)r * NBUK,
            stag + (size_t)r * NBUK * BCAP, E_r[r]);
    scanb_k<<<4, blk, 0, stream>>>(gcur4, gbase4, rp4);
    for (int r = 0; r < 4; r++)
        placeB_k<<<NBUK, blk, 0, stream>>>(
            gcur4 + (size_t)r * NBUK, gbase4 + (size_t)r * (NBUK + 1),
            stag + (size_t)r * NBUK * BCAP, edgesS + eoff[r],
            rp4 + (size_t)r * (NROW + 1), NROW);

    const int* rp_aa = rp4;
    const int* rp_ab = rp4 + (NROW + 1);
    const int* rp_ba = rp4 + 2 * (NROW + 1);
    const int* rp_bb = rp4 + 3 * (NROW + 1);
    const int2* es_aa = edgesS + eoff[0];
    const int2* es_ab = edgesS + eoff[1];
    const int2* es_ba = edgesS + eoff[2];
    const int2* es_bb = edgesS + eoff[3];

    // fp16 views of pre-aggregation buffers
    __half* HaA = (__half*)A0;                       // 100000 x 128 fp16
    __half* HbA = (__half*)A0 + (size_t)NROW * 128;  // 100000 x 128 fp16
    __half* Hc0 = (__half*)A2;                       // 100000 x 64 fp16
    __half* Hc1 = (__half*)A2 + (size_t)NROW * 64;   // 100000 x 64 fp16
    float*  Ua  = A0;                                // u_a f32 (reuses A0 after L0)
    float*  Ub  = A0 + (size_t)NROW * 64;            // u_b f32

    // ================= layer 0, type a =================
    mgemm_k<128, 128, false, false, true><<<gM128, blk, 0, stream>>>(fa, wtH + o0aa, nullptr, (float*)HaA, NA);
    mgemm_k<128, 128, false, false, true><<<gM128, blk, 0, stream>>>(fb, wtH + o0ab, nullptr, (float*)HbA, NB);
    fspmm_att_k<128><<<spg, blk, 0, stream>>>(rp_aa, es_aa, HaA, b0_aa,
                                              rp_ab, es_ab, HbA, b0_ab,
                                              att0_a_W1, att0_a_b1, att0_a_W2, A1, NA);
    // e1_a in A1

    // ================= layer 0, type b =================
    mgemm_k<128, 128, false, false, true><<<gM128, blk, 0, stream>>>(fa, wtH + o0ba, nullptr, (float*)HaA, NA);
    mgemm_k<128, 128, false, false, true><<<gM128, blk, 0, stream>>>(fb, wtH + o0bb, nullptr, (float*)HbA, NB);
    fspmm_att_k<128><<<spg, blk, 0, stream>>>(rp_ba, es_ba, HaA, b0_ba,
                                              rp_bb, es_bb, HbA, b0_bb,
                                              att0_b_W1, att0_b_b1, att0_b_W2, A3, NB);
    // e1_b in A3 (= d_out region)

    // ================= layer 1, type a =================
    mgemm_k<128, 64, false, false, true><<<gM256, blk, 0, stream>>>(A1, wtH + o1aa, nullptr, (float*)Hc0, NA);
    mgemm_k<128, 64, false, false, true><<<gM256, blk, 0, stream>>>(A3, wtH + o1ab, nullptr, (float*)Hc1, NB);
    fspmm_att_k<64><<<spg, blk, 0, stream>>>(rp_aa, es_aa, Hc0, b1_aa,
                                             rp_ab, es_ab, Hc1, b1_ab,
                                             att1_a_W1, att1_a_b1, att1_a_W2, Ua, NA);
    // u_a in Ua (A0)

    // ================= layer 1, type b =================
    mgemm_k<128, 64, false, false, true><<<gM256, blk, 0, stream>>>(A1, wtH + o1ba, nullptr, (float*)Hc0, NA);
    mgemm_k<128, 64, false, false, true><<<gM256, blk, 0, stream>>>(A3, wtH + o1bb, nullptr, (float*)Hc1, NB);
    fspmm_att_k<64><<<spg, blk, 0, stream>>>(rp_ba, es_ba, Hc0, b1_ba,
                                             rp_bb, es_bb, Hc1, b1_bb,
                                             att1_b_W1, att1_b_b1, att1_b_W2, Ub, NB);
    // u_b in Ub (A0 + 6.4M floats)

    // ================= final projection =================
    mgemm_k<64,  64, true,  false, false><<<gM256, blk, 0, stream>>>(Ua, wtH + ofau, bf_a, out, NA);
    mgemm_k<128, 64, false, true,  false><<<gM256, blk, 0, stream>>>(fa, wtH + ofaf, nullptr, out, NA);
    mgemm_k<64,  64, true,  false, false><<<gM256, blk, 0, stream>>>(Ub, wtH + ofbu, bf_b, out + (size_t)NA * OUTD, NB);
    mgemm_k<128, 64, false, true,  false><<<gM256, blk, 0, stream>>>(fb, wtH + ofbf, nullptr, out + (size_t)NA * OUTD, NB);
}

// Round 6
// 1506.730 us; speedup vs baseline: 1.2531x; 1.2531x over previous
//
#include <hip/hip_runtime.h>
#include <hip/hip_fp16.h>
#include <math.h>

#define NA 100000
#define NB 100000
#define NROW 100000   // all four relations have 100000 output rows
#define FT 128
#define H1 128
#define H2 64
#define OUTD 64

#define RBITS 8
#define NBUK  ((NROW + 255) >> 8)     // 391 buckets of 256 rows
#define BCAP  4992                    // staging capacity per bucket
#define CHUNK 4096                    // edges per binA block

typedef __attribute__((ext_vector_type(8))) _Float16 f16x8;
typedef __attribute__((ext_vector_type(4))) float f32x4;

// ---------------- zero fill (small int arrays) ----------------
__global__ __launch_bounds__(256) void zero_k(float4* __restrict__ p, int n4) {
    int i = blockIdx.x * 256 + threadIdx.x;
    if (i < n4) p[i] = make_float4(0.f, 0.f, 0.f, 0.f);
}

// ---------------- weight convert: f32 row-major [K][N] -> fp16 col-major [N][K]
struct WJob { const float* src; int K; int N; int dstoff; };
struct WJobs { WJob j[16]; };
__global__ __launch_bounds__(256) void cvtw_k(WJobs jb, __half* __restrict__ dst) {
    const WJob w = jb.j[blockIdx.x];
    const int KN = w.K * w.N;
    __half* d = dst + w.dstoff;
    for (int i = threadIdx.x; i < KN; i += 256) {
        const int k = i / w.N, n = i - k * w.N;
        d[n * w.K + k] = (__half)w.src[i];
    }
}

// ---------------- CSR build phase A: LDS bucket binning ----------------
__global__ __launch_bounds__(256) void binA_k(
    const int* __restrict__ rows, const int* __restrict__ cols,
    const float* __restrict__ vals, int* __restrict__ gcur,
    int2* __restrict__ stag, int E)
{
    __shared__ int lcnt[NBUK];
    __shared__ int lcnt2[NBUK];
    __shared__ int loff[NBUK + 1];
    __shared__ int gb[NBUK];
    __shared__ int2 sbuf[CHUNK];
    __shared__ int wsum[4];

    const int t = threadIdx.x;
    const int base = blockIdx.x * CHUNK;
    const int n = min(CHUNK, E - base);

    for (int i = t; i < NBUK; i += 256) { lcnt[i] = 0; lcnt2[i] = 0; }
    __syncthreads();

    for (int i = t; i < n; i += 256)
        atomicAdd(&lcnt[rows[base + i] >> RBITS], 1);
    __syncthreads();

    {
        const int i0 = 2 * t, i1 = 2 * t + 1;
        int a = (i0 < NBUK) ? lcnt[i0] : 0;
        int b = (i1 < NBUK) ? lcnt[i1] : 0;
        int s = a + b;
        int inc = s;
#pragma unroll
        for (int m = 1; m < 64; m <<= 1) {
            int u = __shfl_up(inc, m);
            if ((t & 63) >= m) inc += u;
        }
        if ((t & 63) == 63) wsum[t >> 6] = inc;
        __syncthreads();
        int woff = 0;
        const int w = t >> 6;
        for (int i = 0; i < 4; i++) if (i < w) woff += wsum[i];
        const int ex = inc - s + woff;
        if (i0 <= NBUK) loff[i0] = ex;
        if (i1 <= NBUK) loff[i1] = ex + a;
    }
    __syncthreads();

    for (int b = t; b < NBUK; b += 256) {
        const int c = lcnt[b];
        gb[b] = c ? atomicAdd(&gcur[b], c) : 0;
    }
    __syncthreads();

    for (int i = t; i < n; i += 256) {
        const int r = rows[base + i];
        const int c = cols[base + i];
        const float v = vals[base + i];
        const int b = r >> RBITS;
        const int rank = atomicAdd(&lcnt2[b], 1);
        sbuf[loff[b] + rank] = make_int2(c | ((r & 255) << 17), __float_as_int(v));
    }
    __syncthreads();

    for (int s = t; s < n; s += 256) {
        int lo = 0, hi = NBUK - 1;
        while (lo < hi) {
            const int mid = (lo + hi + 1) >> 1;
            if (loff[mid] <= s) lo = mid; else hi = mid - 1;
        }
        const int idx = gb[lo] + (s - loff[lo]);
        if (idx < BCAP) stag[(size_t)lo * BCAP + idx] = sbuf[s];
    }
}

// ---------------- CSR build: scan bucket totals (1 block per relation) ------
__global__ __launch_bounds__(256) void scanb_k(const int* __restrict__ gcur4,
                                               int* __restrict__ gbase4,
                                               int* __restrict__ rp4)
{
    __shared__ int wsum[4];
    const int rel = blockIdx.x;
    const int* gc = gcur4 + rel * NBUK;
    int* gbase = gbase4 + rel * (NBUK + 1);
    const int t = threadIdx.x;
    const int i0 = 2 * t, i1 = 2 * t + 1;
    int a = (i0 < NBUK) ? gc[i0] : 0;
    int b = (i1 < NBUK) ? gc[i1] : 0;
    int s = a + b;
    int inc = s;
#pragma unroll
    for (int m = 1; m < 64; m <<= 1) {
        int u = __shfl_up(inc, m);
        if ((t & 63) >= m) inc += u;
    }
    if ((t & 63) == 63) wsum[t >> 6] = inc;
    __syncthreads();
    int woff = 0;
    const int w = t >> 6;
    for (int i = 0; i < 4; i++) if (i < w) woff += wsum[i];
    const int ex = inc - s + woff;
    if (i0 <= NBUK) gbase[i0] = ex;
    if (i1 <= NBUK) gbase[i1] = ex + a;
    if (t == 255) rp4[(size_t)rel * (NROW + 1) + NROW] = ex + s;
}

// ---------------- CSR build phase B: per-bucket place + rp ----------------
__global__ __launch_bounds__(256) void placeB_k(
    const int* __restrict__ gcur, const int* __restrict__ gbase,
    const int2* __restrict__ stag, int2* __restrict__ edgesS,
    int* __restrict__ rp, int Nrow)
{
    __shared__ int hist[256];
    __shared__ int hoff[256];
    __shared__ int hcur[256];
    __shared__ int2 obuf[BCAP];
    __shared__ int wsum[4];

    const int b = blockIdx.x;
    const int t = threadIdx.x;
    const int n = min(gcur[b], BCAP);
    const int2* src = stag + (size_t)b * BCAP;
    const int fbase = gbase[b];

    hist[t] = 0; hcur[t] = 0;
    __syncthreads();
    for (int s = t; s < n; s += 256)
        atomicAdd(&hist[(src[s].x >> 17) & 255], 1);
    __syncthreads();
    {
        const int a = hist[t];
        int inc = a;
#pragma unroll
        for (int m = 1; m < 64; m <<= 1) {
            int u = __shfl_up(inc, m);
            if ((t & 63) >= m) inc += u;
        }
        if ((t & 63) == 63) wsum[t >> 6] = inc;
        __syncthreads();
        int woff = 0;
        const int w = t >> 6;
        for (int i = 0; i < 4; i++) if (i < w) woff += wsum[i];
        hoff[t] = inc - a + woff;
    }
    __syncthreads();
    const int row = (b << RBITS) + t;
    if (row < Nrow) rp[row] = fbase + hoff[t];
    for (int s = t; s < n; s += 256) {
        const int2 ev = src[s];
        const int rloc = (ev.x >> 17) & 255;
        const int rank = atomicAdd(&hcur[rloc], 1);
        obuf[hoff[rloc] + rank] = make_int2(ev.x & 0x1FFFF, ev.y);
    }
    __syncthreads();
    for (int s = t; s < n; s += 256)
        edgesS[fbase + s] = obuf[s];
}

// ---------------- SpMM (CSR gather), fused bias + LeakyReLU ----------------
template<int F>
__global__ __launch_bounds__(256) void spmm_csr_k(
    const int* __restrict__ rp, const int2* __restrict__ edges,
    const __half* __restrict__ X,
    const float* __restrict__ bias, float* __restrict__ out, int N)
{
    const int wid  = (blockIdx.x * 256 + threadIdx.x) >> 6;
    const int lane = threadIdx.x & 63;
    if (wid >= N) return;
    const int s = rp[wid];
    const int e = rp[wid + 1];

    if (F == 128) {
        float ax = 0.f, ay = 0.f;
        const __half2* Xl = (const __half2*)X + lane;   // row c -> Xl[c * 64]
        int j = s;
        for (; j + 3 < e; j += 4) {
            int2 e0 = edges[j], e1 = edges[j+1], e2 = edges[j+2], e3 = edges[j+3];
            float2 x0 = __half22float2(Xl[(size_t)e0.x * 64]);
            float2 x1 = __half22float2(Xl[(size_t)e1.x * 64]);
            float2 x2 = __half22float2(Xl[(size_t)e2.x * 64]);
            float2 x3 = __half22float2(Xl[(size_t)e3.x * 64]);
            const float v0 = __int_as_float(e0.y), v1 = __int_as_float(e1.y);
            const float v2 = __int_as_float(e2.y), v3 = __int_as_float(e3.y);
            ax += v0 * x0.x + v1 * x1.x + v2 * x2.x + v3 * x3.x;
            ay += v0 * x0.y + v1 * x1.y + v2 * x2.y + v3 * x3.y;
        }
        for (; j < e; j++) {
            int2 ev = edges[j];
            float2 x = __half22float2(Xl[(size_t)ev.x * 64]);
            const float v = __int_as_float(ev.y);
            ax += v * x.x; ay += v * x.y;
        }
        ax += bias[2 * lane];
        ay += bias[2 * lane + 1];
        ax = ax > 0.f ? ax : 0.01f * ax;
        ay = ay > 0.f ? ay : 0.01f * ay;
        float2* dst = (float2*)(out + (size_t)wid * F + 2 * lane);
        *dst = make_float2(ax, ay);
    } else {
        float a = 0.f;
        const __half* Xl = X + lane;                    // row c -> Xl[c * 64]
        int j = s;
        for (; j + 3 < e; j += 4) {
            int2 e0 = edges[j], e1 = edges[j+1], e2 = edges[j+2], e3 = edges[j+3];
            float x0 = __half2float(Xl[(size_t)e0.x * 64]);
            float x1 = __half2float(Xl[(size_t)e1.x * 64]);
            float x2 = __half2float(Xl[(size_t)e2.x * 64]);
            float x3 = __half2float(Xl[(size_t)e3.x * 64]);
            a += __int_as_float(e0.y) * x0 + __int_as_float(e1.y) * x1
               + __int_as_float(e2.y) * x2 + __int_as_float(e3.y) * x3;
        }
        for (; j < e; j++) {
            int2 ev = edges[j];
            a += __int_as_float(ev.y) * __half2float(Xl[(size_t)ev.x * 64]);
        }
        a += bias[lane];
        a = a > 0.f ? a : 0.01f * a;
        out[(size_t)wid * F + lane] = a;
    }
}

// ---------------- MFMA GEMM: C = A@W [+bias] [+C], optional fp16 out -------
template<int K, int BN, bool BIAS, bool ACCUM, bool HOUT>
__global__ __launch_bounds__(256) void mgemm_k(
    const float* __restrict__ A,
    const __half* __restrict__ Wt,
    const float* __restrict__ bias,
    float* __restrict__ C, int M)
{
    constexpr int BM = (BN == 128) ? 128 : 256;
    constexpr int WN = BN / 64;          // waves along N
    const int t = threadIdx.x;
    const int wid = t >> 6;
    const int lane = t & 63;
    const int wr = wid / WN;
    const int wc = wid - wr * WN;
    const int row0 = blockIdx.x * BM + wr * 64;
    const int col0 = wc * 64;
    const int lrow = lane & 15;
    const int kg = lane >> 4;

    f32x4 acc[4][4];
#pragma unroll
    for (int i = 0; i < 4; i++)
#pragma unroll
        for (int j = 0; j < 4; j++) acc[i][j] = (f32x4){0.f, 0.f, 0.f, 0.f};

    const float* ap[4];
#pragma unroll
    for (int i = 0; i < 4; i++) {
        int r = row0 + i * 16 + lrow;
        r = r < M ? r : M - 1;           // clamp: loads valid, store masked
        ap[i] = A + (size_t)r * K + kg * 8;
    }
    const __half* bp[4];
#pragma unroll
    for (int j = 0; j < 4; j++)
        bp[j] = Wt + (size_t)(col0 + j * 16 + lrow) * K + kg * 8;

#pragma unroll
    for (int k0 = 0; k0 < K; k0 += 32) {
        f16x8 af[4], bf[4];
#pragma unroll
        for (int i = 0; i < 4; i++) {
            const f32x4 lo = *(const f32x4*)(ap[i] + k0);
            const f32x4 hi = *(const f32x4*)(ap[i] + k0 + 4);
            f16x8 v;
            v[0] = (_Float16)lo.x; v[1] = (_Float16)lo.y;
            v[2] = (_Float16)lo.z; v[3] = (_Float16)lo.w;
            v[4] = (_Float16)hi.x; v[5] = (_Float16)hi.y;
            v[6] = (_Float16)hi.z; v[7] = (_Float16)hi.w;
            af[i] = v;
        }
#pragma unroll
        for (int j = 0; j < 4; j++)
            bf[j] = *(const f16x8*)(bp[j] + k0);
#pragma unroll
        for (int i = 0; i < 4; i++)
#pragma unroll
            for (int j = 0; j < 4; j++)
                acc[i][j] = __builtin_amdgcn_mfma_f32_16x16x32_f16(af[i], bf[j], acc[i][j], 0, 0, 0);
    }

#pragma unroll
    for (int i = 0; i < 4; i++) {
#pragma unroll
        for (int r = 0; r < 4; r++) {
            const int row = row0 + i * 16 + kg * 4 + r;
            if (row < M) {
#pragma unroll
                for (int j = 0; j < 4; j++) {
                    const int col = col0 + j * 16 + lrow;
                    float v = acc[i][j][r];
                    if (BIAS) v += bias[col];
                    if (HOUT) {
                        ((__half*)C)[(size_t)row * BN + col] = (__half)v;
                    } else {
                        float* cp = C + (size_t)row * BN + col;
                        if (ACCUM) v += *cp;
                        *cp = v;
                    }
                }
            }
        }
    }
}

// ---------------- semantic attention, MFMA scores + LDS blend ----------------
// NT=32 rows/block, 4 waves: wave w -> relation p=w&1, row-group rg=w>>1.
// Scores S = g@W1 via mfma_16x16x32_f16 (A from swizzled f32 LDS + cvt,
// B from fp16 col-major W1 in global/L1). tanh+*W2 per lane, 4 shfl_xor
// j-reduction, then softmax blend from the f32 LDS copies.
template<int D, int H>
__global__ __launch_bounds__(256) void att2_k(
    const float* __restrict__ g0, const float* __restrict__ g1,
    const __half* __restrict__ W1h, const float* __restrict__ b1,
    const float* __restrict__ W2, float* __restrict__ eo, int N)
{
    constexpr int NT = 32;
    constexpr int D4 = D / 4;
    constexpr int KSTEPS = D / 32;
    constexpr int JT = H / 16;
    __shared__ float sg0[NT * D];
    __shared__ float sg1[NT * D];
    __shared__ float sw[2][NT];
    __shared__ float sbeta[2][NT];

    const int t = threadIdx.x;
    const int n0 = blockIdx.x * NT;

    for (int i = t; i < NT * D4; i += 256) {
        const int n = i / D4;
        const int slot = i - n * D4;
        float4 v0 = make_float4(0.f, 0.f, 0.f, 0.f), v1 = v0;
        if (n0 + n < N) {
            v0 = ((const float4*)(g0 + (size_t)(n0 + n) * D))[slot];
            v1 = ((const float4*)(g1 + (size_t)(n0 + n) * D))[slot];
        }
        const int ds = n * D4 + (slot ^ (n & 7));   // XOR-swizzle vs bank conflicts
        ((float4*)sg0)[ds] = v0;
        ((float4*)sg1)[ds] = v1;
    }
    __syncthreads();

    {
        const int w = t >> 6;
        const int lane = t & 63;
        const int p = w & 1;
        const int rg = w >> 1;
        const float* sg = p ? sg1 : sg0;
        const int lrow = lane & 15;
        const int kg = lane >> 4;
        const int row = rg * 16 + lrow;

        f32x4 acc[JT];
#pragma unroll
        for (int jt = 0; jt < JT; jt++) acc[jt] = (f32x4){0.f, 0.f, 0.f, 0.f};
#pragma unroll
        for (int kt = 0; kt < KSTEPS; kt++) {
            const int s0 = kt * 8 + kg * 2;
            const float4 a0 = ((const float4*)sg)[row * D4 + (s0 ^ (row & 7))];
            const float4 a1 = ((const float4*)sg)[row * D4 + ((s0 + 1) ^ (row & 7))];
            f16x8 af;
            af[0] = (_Float16)a0.x; af[1] = (_Float16)a0.y;
            af[2] = (_Float16)a0.z; af[3] = (_Float16)a0.w;
            af[4] = (_Float16)a1.x; af[5] = (_Float16)a1.y;
            af[6] = (_Float16)a1.z; af[7] = (_Float16)a1.w;
#pragma unroll
            for (int jt = 0; jt < JT; jt++) {
                const f16x8 bf = *(const f16x8*)(W1h + (size_t)(jt * 16 + lrow) * D + kt * 32 + kg * 8);
                acc[jt] = __builtin_amdgcn_mfma_f32_16x16x32_f16(af, bf, acc[jt], 0, 0, 0);
            }
        }
#pragma unroll
        for (int r = 0; r < 4; r++) {
            float v = 0.f;
#pragma unroll
            for (int jt = 0; jt < JT; jt++) {
                const int j = jt * 16 + lrow;
                v += tanhf(acc[jt][r] + b1[j]) * W2[j];
            }
            v += __shfl_xor(v, 1);
            v += __shfl_xor(v, 2);
            v += __shfl_xor(v, 4);
            v += __shfl_xor(v, 8);
            if (lrow == 0) sw[p][rg * 16 + kg * 4 + r] = v;
        }
    }
    __syncthreads();
    if (t < NT) {
        const float w0 = sw[0][t], w1 = sw[1][t];
        const float mx = fmaxf(w0, w1);
        const float e0 = expf(w0 - mx), e1 = expf(w1 - mx);
        const float inv = 1.f / (e0 + e1);
        sbeta[0][t] = e0 * inv;
        sbeta[1][t] = e1 * inv;
    }
    __syncthreads();
    for (int i = t; i < NT * D4; i += 256) {
        const int n = i / D4;
        const int slot = i - n * D4;
        if (n0 + n < N) {
            const int ds = n * D4 + (slot ^ (n & 7));
            const float4 a = ((const float4*)sg0)[ds];
            const float4 b = ((const float4*)sg1)[ds];
            const float c0 = sbeta[0][n], c1 = sbeta[1][n];
            float4 o;
            o.x = c0 * a.x + c1 * b.x;
            o.y = c0 * a.y + c1 * b.y;
            o.z = c0 * a.z + c1 * b.z;
            o.w = c0 * a.w + c1 * b.w;
            ((float4*)(eo + (size_t)(n0 + n) * D))[slot] = o;
        }
    }
}

// ---------------- launch ----------------
extern "C" void kernel_launch(void* const* d_in, const int* in_sizes, int n_in,
                              void* d_out, int out_size, void* d_ws, size_t ws_size,
                              hipStream_t stream)
{
    const float* feat = (const float*)d_in[0];
    const int*   row_aa = (const int*)d_in[1];
    const int*   col_aa = (const int*)d_in[2];
    const float* val_aa = (const float*)d_in[3];
    const int*   row_ab = (const int*)d_in[4];
    const int*   col_ab = (const int*)d_in[5];
    const float* val_ab = (const float*)d_in[6];
    const int*   row_ba = (const int*)d_in[7];
    const int*   col_ba = (const int*)d_in[8];
    const float* val_ba = (const float*)d_in[9];
    const int*   row_bb = (const int*)d_in[10];
    const int*   col_bb = (const int*)d_in[11];
    const float* val_bb = (const float*)d_in[12];
    const float* W0_aa = (const float*)d_in[13]; const float* b0_aa = (const float*)d_in[14];
    const float* W1_aa = (const float*)d_in[15]; const float* b1_aa = (const float*)d_in[16];
    const float* W0_ab = (const float*)d_in[17]; const float* b0_ab = (const float*)d_in[18];
    const float* W1_ab = (const float*)d_in[19]; const float* b1_ab = (const float*)d_in[20];
    const float* W0_ba = (const float*)d_in[21]; const float* b0_ba = (const float*)d_in[22];
    const float* W1_ba = (const float*)d_in[23]; const float* b1_ba = (const float*)d_in[24];
    const float* W0_bb = (const float*)d_in[25]; const float* b0_bb = (const float*)d_in[26];
    const float* W1_bb = (const float*)d_in[27]; const float* b1_bb = (const float*)d_in[28];
    const float* att0_a_W1 = (const float*)d_in[29];
    const float* att0_a_b1 = (const float*)d_in[30];
    const float* att0_a_W2 = (const float*)d_in[31];
    const float* att1_a_W1 = (const float*)d_in[32];
    const float* att1_a_b1 = (const float*)d_in[33];
    const float* att1_a_W2 = (const float*)d_in[34];
    const float* Wf_a = (const float*)d_in[35]; const float* bf_a = (const float*)d_in[36];
    const float* att0_b_W1 = (const float*)d_in[37];
    const float* att0_b_b1 = (const float*)d_in[38];
    const float* att0_b_W2 = (const float*)d_in[39];
    const float* att1_b_W1 = (const float*)d_in[40];
    const float* att1_b_b1 = (const float*)d_in[41];
    const float* att1_b_W2 = (const float*)d_in[42];
    const float* Wf_b = (const float*)d_in[43]; const float* bf_b = (const float*)d_in[44];

    const int E_r[4] = { in_sizes[1], in_sizes[4], in_sizes[7], in_sizes[10] };
    const int* rows_r[4] = { row_aa, row_ab, row_ba, row_bb };
    const int* cols_r[4] = { col_aa, col_ab, col_ba, col_bb };
    const float* vals_r[4] = { val_aa, val_ab, val_ba, val_bb };

    const size_t RSZ = (size_t)12800000;
    size_t Etot = (size_t)E_r[0] + E_r[1] + E_r[2] + E_r[3];
    size_t need = (3 * RSZ + (size_t)4 * (NROW + 1) + (size_t)4 * NBUK
                   + (size_t)4 * (NBUK + 1) + 2 * Etot + 66624 + 64) * 4;
    if (ws_size < need) return;

    float* ws = (float*)d_ws;
    float* A0 = ws;
    float* A1 = ws + RSZ;
    float* A2 = ws + 2 * RSZ;
    float* A3 = (float*)d_out;            // e1_b lives here until final projection
    int*   rp4    = (int*)(ws + 3 * RSZ);
    int*   gcur4  = rp4 + (size_t)4 * (NROW + 1);
    int*   gbase4 = gcur4 + (size_t)4 * NBUK;
    int2*  edgesS = (int2*)(gbase4 + (size_t)4 * (NBUK + 1));
    __half* wtH   = (__half*)((int*)edgesS + 2 * Etot);   // 133120 halves, 16B-aligned
    int2*  stag   = (int2*)ws;            // staging overlaps A0/A1 (unused during build)

    size_t eoff[4];
    eoff[0] = 0; eoff[1] = eoff[0] + E_r[0];
    eoff[2] = eoff[1] + E_r[1]; eoff[3] = eoff[2] + E_r[2];

    float* out = (float*)d_out;
    const float* fa = feat;
    const float* fb = feat + (size_t)NA * FT;

    const dim3 blk(256);
    const int gM128 = (NROW + 127) / 128;      // mgemm BN=128 grid
    const int gM256 = (NROW + 255) / 256;      // mgemm BN=64 grid
    const int spg = (NROW * 64 + 255) / 256;   // spmm: one wave per row
    const int ag  = (NROW + 31) / 32;          // att2 NT=32

    // fp16 col-major weight offsets (halves)
    const int o0aa = 0,      o0ab = 16384, o0ba = 32768, o0bb = 49152;
    const int o1aa = 65536,  o1ab = 73728, o1ba = 81920, o1bb = 90112;
    const int ofau = 98304,  ofaf = 102400, ofbu = 110592, ofbf = 114688;
    const int oA0a = 122880, oA0b = 126976, oA1a = 131072, oA1b = 132096;

    // ================= weight conversion + CSR build =================
    zero_k<<<(NBUK + 255) / 256, blk, 0, stream>>>((float4*)gcur4, NBUK);  // 4*NBUK ints
    {
        WJobs jb;
        jb.j[0]  = { W0_aa, 128, 128, o0aa };
        jb.j[1]  = { W0_ab, 128, 128, o0ab };
        jb.j[2]  = { W0_ba, 128, 128, o0ba };
        jb.j[3]  = { W0_bb, 128, 128, o0bb };
        jb.j[4]  = { W1_aa, 128, 64,  o1aa };
        jb.j[5]  = { W1_ab, 128, 64,  o1ab };
        jb.j[6]  = { W1_ba, 128, 64,  o1ba };
        jb.j[7]  = { W1_bb, 128, 64,  o1bb };
        jb.j[8]  = { Wf_a,            64,  64, ofau };
        jb.j[9]  = { Wf_a + 64 * 64,  128, 64, ofaf };
        jb.j[10] = { Wf_b,            64,  64, ofbu };
        jb.j[11] = { Wf_b + 64 * 64,  128, 64, ofbf };
        jb.j[12] = { att0_a_W1, 128, 32, oA0a };
        jb.j[13] = { att0_b_W1, 128, 32, oA0b };
        jb.j[14] = { att1_a_W1, 64,  16, oA1a };
        jb.j[15] = { att1_b_W1, 64,  16, oA1b };
        cvtw_k<<<16, blk, 0, stream>>>(jb, wtH);
    }
    for (int r = 0; r < 4; r++)
        binA_k<<<(E_r[r] + CHUNK - 1) / CHUNK, blk, 0, stream>>>(
            rows_r[r], cols_r[r], vals_r[r], gcur4 + (size_t)r * NBUK,
            stag + (size_t)r * NBUK * BCAP, E_r[r]);
    scanb_k<<<4, blk, 0, stream>>>(gcur4, gbase4, rp4);
    for (int r = 0; r < 4; r++)
        placeB_k<<<NBUK, blk, 0, stream>>>(
            gcur4 + (size_t)r * NBUK, gbase4 + (size_t)r * (NBUK + 1),
            stag + (size_t)r * NBUK * BCAP, edgesS + eoff[r],
            rp4 + (size_t)r * (NROW + 1), NROW);

    const int* rp_aa = rp4;
    const int* rp_ab = rp4 + (NROW + 1);
    const int* rp_ba = rp4 + 2 * (NROW + 1);
    const int* rp_bb = rp4 + 3 * (NROW + 1);
    const int2* es_aa = edgesS + eoff[0];
    const int2* es_ab = edgesS + eoff[1];
    const int2* es_ba = edgesS + eoff[2];
    const int2* es_bb = edgesS + eoff[3];

    const __half* H0 = (const __half*)A0;   // fp16 view of the pre-agg buffer

    // ================= layer 0, type a =================
    mgemm_k<128, 128, false, false, true><<<gM128, blk, 0, stream>>>(fa, wtH + o0aa, nullptr, A0, NA);
    spmm_csr_k<128><<<spg, blk, 0, stream>>>(rp_aa, es_aa, H0, b0_aa, A1, NA);
    mgemm_k<128, 128, false, false, true><<<gM128, blk, 0, stream>>>(fb, wtH + o0ab, nullptr, A0, NB);
    spmm_csr_k<128><<<spg, blk, 0, stream>>>(rp_ab, es_ab, H0, b0_ab, A2, NA);
    att2_k<128, 32><<<ag, blk, 0, stream>>>(A1, A2, wtH + oA0a, att0_a_b1, att0_a_W2, A1, NA);
    // e1_a in A1

    // ================= layer 0, type b =================
    mgemm_k<128, 128, false, false, true><<<gM128, blk, 0, stream>>>(fa, wtH + o0ba, nullptr, A0, NA);
    spmm_csr_k<128><<<spg, blk, 0, stream>>>(rp_ba, es_ba, H0, b0_ba, A3, NB);
    mgemm_k<128, 128, false, false, true><<<gM128, blk, 0, stream>>>(fb, wtH + o0bb, nullptr, A0, NB);
    spmm_csr_k<128><<<spg, blk, 0, stream>>>(rp_bb, es_bb, H0, b0_bb, A2, NB);
    att2_k<128, 32><<<ag, blk, 0, stream>>>(A3, A2, wtH + oA0b, att0_b_b1, att0_b_W2, A3, NB);
    // e1_b in A3 (= d_out region)

    float* A0lo = A0;            float* A0hi = A0 + RSZ / 2;
    float* A2lo = A2;            float* A2hi = A2 + RSZ / 2;
    const __half* H0lo = (const __half*)A0lo;
    const __half* H2lo = (const __half*)A2lo;

    // ================= layer 1, type a =================
    mgemm_k<128, 64, false, false, true><<<gM256, blk, 0, stream>>>(A1, wtH + o1aa, nullptr, A0lo, NA);
    spmm_csr_k<64><<<spg, blk, 0, stream>>>(rp_aa, es_aa, H0lo, b1_aa, A0hi, NA);
    mgemm_k<128, 64, false, false, true><<<gM256, blk, 0, stream>>>(A3, wtH + o1ab, nullptr, A2lo, NB);
    spmm_csr_k<64><<<spg, blk, 0, stream>>>(rp_ab, es_ab, H2lo, b1_ab, A2hi, NA);
    att2_k<64, 16><<<ag, blk, 0, stream>>>(A0hi, A2hi, wtH + oA1a, att1_a_b1, att1_a_W2, A0hi, NA);
    // u_a in A0hi

    // ================= layer 1, type b =================
    mgemm_k<128, 64, false, false, true><<<gM256, blk, 0, stream>>>(A1, wtH + o1ba, nullptr, A2lo, NA);
    spmm_csr_k<64><<<spg, blk, 0, stream>>>(rp_ba, es_ba, H2lo, b1_ba, A2hi, NB);
    mgemm_k<128, 64, false, false, true><<<gM256, blk, 0, stream>>>(A3, wtH + o1bb, nullptr, A2lo, NB);
    spmm_csr_k<64><<<spg, blk, 0, stream>>>(rp_bb, es_bb, H2lo, b1_bb, A0lo, NB);
    att2_k<64, 16><<<ag, blk, 0, stream>>>(A2hi, A0lo, wtH + oA1b, att1_b_b1, att1_b_W2, A2hi, NB);
    // u_b in A2hi

    // ================= final projection =================
    mgemm_k<64,  64, true,  false, false><<<gM256, blk, 0, stream>>>(A0hi, wtH + ofau, bf_a, out, NA);
    mgemm_k<128, 64, false, true,  false><<<gM256, blk, 0, stream>>>(fa, wtH + ofaf, nullptr, out, NA);
    mgemm_k<64,  64, true,  false, false><<<gM256, blk, 0, stream>>>(A2hi, wtH + ofbu, bf_b, out + (size_t)NA * OUTD, NB);
    mgemm_k<128, 64, false, true,  false><<<gM256, blk, 0, stream>>>(fb, wtH + ofbf, nullptr, out + (size_t)NA * OUTD, NB);
}

// Round 7
// 1264.398 us; speedup vs baseline: 1.4933x; 1.1917x over previous
//
#include <hip/hip_runtime.h>
#include <hip/hip_fp16.h>
#include <math.h>

#define NA 100000
#define NB 100000
#define NROW 100000   // all four relations have 100000 output rows
#define FT 128
#define H1 128
#define H2 64
#define OUTD 64

#define RBITS 8
#define NBUK  ((NROW + 255) >> 8)     // 391 buckets of 256 rows
#define BCAP  4992                    // staging capacity per bucket
#define CHUNK 4096                    // edges per binA block

typedef __attribute__((ext_vector_type(8))) _Float16 f16x8;
typedef __attribute__((ext_vector_type(4))) float f32x4;

// ---------------- zero fill (small int arrays) ----------------
__global__ __launch_bounds__(256) void zero_k(float4* __restrict__ p, int n4) {
    int i = blockIdx.x * 256 + threadIdx.x;
    if (i < n4) p[i] = make_float4(0.f, 0.f, 0.f, 0.f);
}

// ---------------- weight convert: f32 row-major [K][N] -> fp16 col-major [N][K]
struct WJob { const float* src; int K; int N; int dstoff; };
struct WJobs { WJob j[16]; };
__global__ __launch_bounds__(256) void cvtw_k(WJobs jb, __half* __restrict__ dst) {
    const WJob w = jb.j[blockIdx.x];
    const int KN = w.K * w.N;
    __half* d = dst + w.dstoff;
    for (int i = threadIdx.x; i < KN; i += 256) {
        const int k = i / w.N, n = i - k * w.N;
        d[n * w.K + k] = (__half)w.src[i];
    }
}

// ---------------- CSR build phase A: LDS bucket binning ----------------
__global__ __launch_bounds__(256) void binA_k(
    const int* __restrict__ rows, const int* __restrict__ cols,
    const float* __restrict__ vals, int* __restrict__ gcur,
    int2* __restrict__ stag, int E)
{
    __shared__ int lcnt[NBUK];
    __shared__ int lcnt2[NBUK];
    __shared__ int loff[NBUK + 1];
    __shared__ int gb[NBUK];
    __shared__ int2 sbuf[CHUNK];
    __shared__ int wsum[4];

    const int t = threadIdx.x;
    const int base = blockIdx.x * CHUNK;
    const int n = min(CHUNK, E - base);

    for (int i = t; i < NBUK; i += 256) { lcnt[i] = 0; lcnt2[i] = 0; }
    __syncthreads();

    for (int i = t; i < n; i += 256)
        atomicAdd(&lcnt[rows[base + i] >> RBITS], 1);
    __syncthreads();

    {
        const int i0 = 2 * t, i1 = 2 * t + 1;
        int a = (i0 < NBUK) ? lcnt[i0] : 0;
        int b = (i1 < NBUK) ? lcnt[i1] : 0;
        int s = a + b;
        int inc = s;
#pragma unroll
        for (int m = 1; m < 64; m <<= 1) {
            int u = __shfl_up(inc, m);
            if ((t & 63) >= m) inc += u;
        }
        if ((t & 63) == 63) wsum[t >> 6] = inc;
        __syncthreads();
        int woff = 0;
        const int w = t >> 6;
        for (int i = 0; i < 4; i++) if (i < w) woff += wsum[i];
        const int ex = inc - s + woff;
        if (i0 <= NBUK) loff[i0] = ex;
        if (i1 <= NBUK) loff[i1] = ex + a;
    }
    __syncthreads();

    for (int b = t; b < NBUK; b += 256) {
        const int c = lcnt[b];
        gb[b] = c ? atomicAdd(&gcur[b], c) : 0;
    }
    __syncthreads();

    for (int i = t; i < n; i += 256) {
        const int r = rows[base + i];
        const int c = cols[base + i];
        const float v = vals[base + i];
        const int b = r >> RBITS;
        const int rank = atomicAdd(&lcnt2[b], 1);
        sbuf[loff[b] + rank] = make_int2(c | ((r & 255) << 17), __float_as_int(v));
    }
    __syncthreads();

    for (int s = t; s < n; s += 256) {
        int lo = 0, hi = NBUK - 1;
        while (lo < hi) {
            const int mid = (lo + hi + 1) >> 1;
            if (loff[mid] <= s) lo = mid; else hi = mid - 1;
        }
        const int idx = gb[lo] + (s - loff[lo]);
        if (idx < BCAP) stag[(size_t)lo * BCAP + idx] = sbuf[s];
    }
}

// ---------------- CSR build: scan bucket totals (1 block per relation) ------
__global__ __launch_bounds__(256) void scanb_k(const int* __restrict__ gcur4,
                                               int* __restrict__ gbase4,
                                               int* __restrict__ rp4)
{
    __shared__ int wsum[4];
    const int rel = blockIdx.x;
    const int* gc = gcur4 + rel * NBUK;
    int* gbase = gbase4 + rel * (NBUK + 1);
    const int t = threadIdx.x;
    const int i0 = 2 * t, i1 = 2 * t + 1;
    int a = (i0 < NBUK) ? gc[i0] : 0;
    int b = (i1 < NBUK) ? gc[i1] : 0;
    int s = a + b;
    int inc = s;
#pragma unroll
    for (int m = 1; m < 64; m <<= 1) {
        int u = __shfl_up(inc, m);
        if ((t & 63) >= m) inc += u;
    }
    if ((t & 63) == 63) wsum[t >> 6] = inc;
    __syncthreads();
    int woff = 0;
    const int w = t >> 6;
    for (int i = 0; i < 4; i++) if (i < w) woff += wsum[i];
    const int ex = inc - s + woff;
    if (i0 <= NBUK) gbase[i0] = ex;
    if (i1 <= NBUK) gbase[i1] = ex + a;
    if (t == 255) rp4[(size_t)rel * (NROW + 1) + NROW] = ex + s;
}

// ---------------- CSR build phase B: per-bucket place + rp ----------------
__global__ __launch_bounds__(256) void placeB_k(
    const int* __restrict__ gcur, const int* __restrict__ gbase,
    const int2* __restrict__ stag, int2* __restrict__ edgesS,
    int* __restrict__ rp, int Nrow)
{
    __shared__ int hist[256];
    __shared__ int hoff[256];
    __shared__ int hcur[256];
    __shared__ int2 obuf[BCAP];
    __shared__ int wsum[4];

    const int b = blockIdx.x;
    const int t = threadIdx.x;
    const int n = min(gcur[b], BCAP);
    const int2* src = stag + (size_t)b * BCAP;
    const int fbase = gbase[b];

    hist[t] = 0; hcur[t] = 0;
    __syncthreads();
    for (int s = t; s < n; s += 256)
        atomicAdd(&hist[(src[s].x >> 17) & 255], 1);
    __syncthreads();
    {
        const int a = hist[t];
        int inc = a;
#pragma unroll
        for (int m = 1; m < 64; m <<= 1) {
            int u = __shfl_up(inc, m);
            if ((t & 63) >= m) inc += u;
        }
        if ((t & 63) == 63) wsum[t >> 6] = inc;
        __syncthreads();
        int woff = 0;
        const int w = t >> 6;
        for (int i = 0; i < 4; i++) if (i < w) woff += wsum[i];
        hoff[t] = inc - a + woff;
    }
    __syncthreads();
    const int row = (b << RBITS) + t;
    if (row < Nrow) rp[row] = fbase + hoff[t];
    for (int s = t; s < n; s += 256) {
        const int2 ev = src[s];
        const int rloc = (ev.x >> 17) & 255;
        const int rank = atomicAdd(&hcur[rloc], 1);
        obuf[hoff[rloc] + rank] = make_int2(ev.x & 0x1FFFF, ev.y);
    }
    __syncthreads();
    for (int s = t; s < n; s += 256)
        edgesS[fbase + s] = obuf[s];
}

// ---------------- SpMM (CSR gather), fused bias + LeakyReLU ----------------
// Multi-row waves: F=128 -> 4 rows/wave (16 lanes x 16B per row),
// F=64 -> 8 rows/wave (8 lanes x 16B). 4-deep unroll gives 16/32 independent
// gathers in flight per wave; exec-masked lanes fetch nothing (no dummy bytes).
template<int F>
__global__ __launch_bounds__(256) void spmm_csr_k(
    const int* __restrict__ rp, const int2* __restrict__ edges,
    const __half* __restrict__ X,
    const float* __restrict__ bias, float* __restrict__ out, int N)
{
    constexpr int LPR = F / 8;          // lanes per row: 16 (F=128) / 8 (F=64)
    constexpr int RPW = 64 / LPR;       // rows per wave: 4 / 8
    const int wave = (blockIdx.x * 256 + threadIdx.x) >> 6;
    const int lane = threadIdx.x & 63;
    const int sub  = lane / LPR;
    const int sl   = lane & (LPR - 1);
    const int row  = wave * RPW + sub;
    const bool rok = row < N;
    const int s = rok ? rp[row] : 0;
    const int e = rok ? rp[row + 1] : 0;

    float acc[8];
#pragma unroll
    for (int k = 0; k < 8; k++) acc[k] = 0.f;

    const __half* Xs = X + sl * 8;      // this lane's 8-col slice of any row
    int j = s;
    for (; j + 3 < e; j += 4) {
        const int2 e0 = edges[j], e1 = edges[j+1], e2 = edges[j+2], e3 = edges[j+3];
        const f16x8 h0 = *(const f16x8*)(Xs + (size_t)e0.x * F);
        const f16x8 h1 = *(const f16x8*)(Xs + (size_t)e1.x * F);
        const f16x8 h2 = *(const f16x8*)(Xs + (size_t)e2.x * F);
        const f16x8 h3 = *(const f16x8*)(Xs + (size_t)e3.x * F);
        const float v0 = __int_as_float(e0.y), v1 = __int_as_float(e1.y);
        const float v2 = __int_as_float(e2.y), v3 = __int_as_float(e3.y);
#pragma unroll
        for (int k = 0; k < 8; k++)
            acc[k] += v0 * (float)h0[k] + v1 * (float)h1[k]
                    + v2 * (float)h2[k] + v3 * (float)h3[k];
    }
    for (; j < e; j++) {
        const int2 ev = edges[j];
        const f16x8 h = *(const f16x8*)(Xs + (size_t)ev.x * F);
        const float v = __int_as_float(ev.y);
#pragma unroll
        for (int k = 0; k < 8; k++) acc[k] += v * (float)h[k];
    }

    if (rok) {
        const float4 b0 = *(const float4*)(bias + sl * 8);
        const float4 b1 = *(const float4*)(bias + sl * 8 + 4);
        float r0 = acc[0] + b0.x, r1 = acc[1] + b0.y;
        float r2 = acc[2] + b0.z, r3 = acc[3] + b0.w;
        float r4 = acc[4] + b1.x, r5 = acc[5] + b1.y;
        float r6 = acc[6] + b1.z, r7 = acc[7] + b1.w;
        r0 = r0 > 0.f ? r0 : 0.01f * r0;
        r1 = r1 > 0.f ? r1 : 0.01f * r1;
        r2 = r2 > 0.f ? r2 : 0.01f * r2;
        r3 = r3 > 0.f ? r3 : 0.01f * r3;
        r4 = r4 > 0.f ? r4 : 0.01f * r4;
        r5 = r5 > 0.f ? r5 : 0.01f * r5;
        r6 = r6 > 0.f ? r6 : 0.01f * r6;
        r7 = r7 > 0.f ? r7 : 0.01f * r7;
        float* op = out + (size_t)row * F + sl * 8;
        *(float4*)op       = make_float4(r0, r1, r2, r3);
        *(float4*)(op + 4) = make_float4(r4, r5, r6, r7);
    }
}

// ---------------- MFMA GEMM: C = A@W [+bias] [+C], optional fp16 out -------
template<int K, int BN, bool BIAS, bool ACCUM, bool HOUT>
__global__ __launch_bounds__(256) void mgemm_k(
    const float* __restrict__ A,
    const __half* __restrict__ Wt,
    const float* __restrict__ bias,
    float* __restrict__ C, int M)
{
    constexpr int BM = (BN == 128) ? 128 : 256;
    constexpr int WN = BN / 64;          // waves along N
    const int t = threadIdx.x;
    const int wid = t >> 6;
    const int lane = t & 63;
    const int wr = wid / WN;
    const int wc = wid - wr * WN;
    const int row0 = blockIdx.x * BM + wr * 64;
    const int col0 = wc * 64;
    const int lrow = lane & 15;
    const int kg = lane >> 4;

    f32x4 acc[4][4];
#pragma unroll
    for (int i = 0; i < 4; i++)
#pragma unroll
        for (int j = 0; j < 4; j++) acc[i][j] = (f32x4){0.f, 0.f, 0.f, 0.f};

    const float* ap[4];
#pragma unroll
    for (int i = 0; i < 4; i++) {
        int r = row0 + i * 16 + lrow;
        r = r < M ? r : M - 1;           // clamp: loads valid, store masked
        ap[i] = A + (size_t)r * K + kg * 8;
    }
    const __half* bp[4];
#pragma unroll
    for (int j = 0; j < 4; j++)
        bp[j] = Wt + (size_t)(col0 + j * 16 + lrow) * K + kg * 8;

#pragma unroll
    for (int k0 = 0; k0 < K; k0 += 32) {
        f16x8 af[4], bf[4];
#pragma unroll
        for (int i = 0; i < 4; i++) {
            const f32x4 lo = *(const f32x4*)(ap[i] + k0);
            const f32x4 hi = *(const f32x4*)(ap[i] + k0 + 4);
            f16x8 v;
            v[0] = (_Float16)lo.x; v[1] = (_Float16)lo.y;
            v[2] = (_Float16)lo.z; v[3] = (_Float16)lo.w;
            v[4] = (_Float16)hi.x; v[5] = (_Float16)hi.y;
            v[6] = (_Float16)hi.z; v[7] = (_Float16)hi.w;
            af[i] = v;
        }
#pragma unroll
        for (int j = 0; j < 4; j++)
            bf[j] = *(const f16x8*)(bp[j] + k0);
#pragma unroll
        for (int i = 0; i < 4; i++)
#pragma unroll
            for (int j = 0; j < 4; j++)
                acc[i][j] = __builtin_amdgcn_mfma_f32_16x16x32_f16(af[i], bf[j], acc[i][j], 0, 0, 0);
    }

#pragma unroll
    for (int i = 0; i < 4; i++) {
#pragma unroll
        for (int r = 0; r < 4; r++) {
            const int row = row0 + i * 16 + kg * 4 + r;
            if (row < M) {
#pragma unroll
                for (int j = 0; j < 4; j++) {
                    const int col = col0 + j * 16 + lrow;
                    float v = acc[i][j][r];
                    if (BIAS) v += bias[col];
                    if (HOUT) {
                        ((__half*)C)[(size_t)row * BN + col] = (__half)v;
                    } else {
                        float* cp = C + (size_t)row * BN + col;
                        if (ACCUM) v += *cp;
                        *cp = v;
                    }
                }
            }
        }
    }
}

// ---------------- semantic attention, MFMA scores + LDS blend ----------------
template<int D, int H>
__global__ __launch_bounds__(256) void att2_k(
    const float* __restrict__ g0, const float* __restrict__ g1,
    const __half* __restrict__ W1h, const float* __restrict__ b1,
    const float* __restrict__ W2, float* __restrict__ eo, int N)
{
    constexpr int NT = 32;
    constexpr int D4 = D / 4;
    constexpr int KSTEPS = D / 32;
    constexpr int JT = H / 16;
    __shared__ float sg0[NT * D];
    __shared__ float sg1[NT * D];
    __shared__ float sw[2][NT];
    __shared__ float sbeta[2][NT];

    const int t = threadIdx.x;
    const int n0 = blockIdx.x * NT;

    for (int i = t; i < NT * D4; i += 256) {
        const int n = i / D4;
        const int slot = i - n * D4;
        float4 v0 = make_float4(0.f, 0.f, 0.f, 0.f), v1 = v0;
        if (n0 + n < N) {
            v0 = ((const float4*)(g0 + (size_t)(n0 + n) * D))[slot];
            v1 = ((const float4*)(g1 + (size_t)(n0 + n) * D))[slot];
        }
        const int ds = n * D4 + (slot ^ (n & 7));   // XOR-swizzle vs bank conflicts
        ((float4*)sg0)[ds] = v0;
        ((float4*)sg1)[ds] = v1;
    }
    __syncthreads();

    {
        const int w = t >> 6;
        const int lane = t & 63;
        const int p = w & 1;
        const int rg = w >> 1;
        const float* sg = p ? sg1 : sg0;
        const int lrow = lane & 15;
        const int kg = lane >> 4;
        const int row = rg * 16 + lrow;

        f32x4 acc[JT];
#pragma unroll
        for (int jt = 0; jt < JT; jt++) acc[jt] = (f32x4){0.f, 0.f, 0.f, 0.f};
#pragma unroll
        for (int kt = 0; kt < KSTEPS; kt++) {
            const int s0 = kt * 8 + kg * 2;
            const float4 a0 = ((const float4*)sg)[row * D4 + (s0 ^ (row & 7))];
            const float4 a1 = ((const float4*)sg)[row * D4 + ((s0 + 1) ^ (row & 7))];
            f16x8 af;
            af[0] = (_Float16)a0.x; af[1] = (_Float16)a0.y;
            af[2] = (_Float16)a0.z; af[3] = (_Float16)a0.w;
            af[4] = (_Float16)a1.x; af[5] = (_Float16)a1.y;
            af[6] = (_Float16)a1.z; af[7] = (_Float16)a1.w;
#pragma unroll
            for (int jt = 0; jt < JT; jt++) {
                const f16x8 bf = *(const f16x8*)(W1h + (size_t)(jt * 16 + lrow) * D + kt * 32 + kg * 8);
                acc[jt] = __builtin_amdgcn_mfma_f32_16x16x32_f16(af, bf, acc[jt], 0, 0, 0);
            }
        }
#pragma unroll
        for (int r = 0; r < 4; r++) {
            float v = 0.f;
#pragma unroll
            for (int jt = 0; jt < JT; jt++) {
                const int j = jt * 16 + lrow;
                v += tanhf(acc[jt][r] + b1[j]) * W2[j];
            }
            v += __shfl_xor(v, 1);
            v += __shfl_xor(v, 2);
            v += __shfl_xor(v, 4);
            v += __shfl_xor(v, 8);
            if (lrow == 0) sw[p][rg * 16 + kg * 4 + r] = v;
        }
    }
    __syncthreads();
    if (t < NT) {
        const float w0 = sw[0][t], w1 = sw[1][t];
        const float mx = fmaxf(w0, w1);
        const float e0 = expf(w0 - mx), e1 = expf(w1 - mx);
        const float inv = 1.f / (e0 + e1);
        sbeta[0][t] = e0 * inv;
        sbeta[1][t] = e1 * inv;
    }
    __syncthreads();
    for (int i = t; i < NT * D4; i += 256) {
        const int n = i / D4;
        const int slot = i - n * D4;
        if (n0 + n < N) {
            const int ds = n * D4 + (slot ^ (n & 7));
            const float4 a = ((const float4*)sg0)[ds];
            const float4 b = ((const float4*)sg1)[ds];
            const float c0 = sbeta[0][n], c1 = sbeta[1][n];
            float4 o;
            o.x = c0 * a.x + c1 * b.x;
            o.y = c0 * a.y + c1 * b.y;
            o.z = c0 * a.z + c1 * b.z;
            o.w = c0 * a.w + c1 * b.w;
            ((float4*)(eo + (size_t)(n0 + n) * D))[slot] = o;
        }
    }
}

// ---------------- launch ----------------
extern "C" void kernel_launch(void* const* d_in, const int* in_sizes, int n_in,
                              void* d_out, int out_size, void* d_ws, size_t ws_size,
                              hipStream_t stream)
{
    const float* feat = (const float*)d_in[0];
    const int*   row_aa = (const int*)d_in[1];
    const int*   col_aa = (const int*)d_in[2];
    const float* val_aa = (const float*)d_in[3];
    const int*   row_ab = (const int*)d_in[4];
    const int*   col_ab = (const int*)d_in[5];
    const float* val_ab = (const float*)d_in[6];
    const int*   row_ba = (const int*)d_in[7];
    const int*   col_ba = (const int*)d_in[8];
    const float* val_ba = (const float*)d_in[9];
    const int*   row_bb = (const int*)d_in[10];
    const int*   col_bb = (const int*)d_in[11];
    const float* val_bb = (const float*)d_in[12];
    const float* W0_aa = (const float*)d_in[13]; const float* b0_aa = (const float*)d_in[14];
    const float* W1_aa = (const float*)d_in[15]; const float* b1_aa = (const float*)d_in[16];
    const float* W0_ab = (const float*)d_in[17]; const float* b0_ab = (const float*)d_in[18];
    const float* W1_ab = (const float*)d_in[19]; const float* b1_ab = (const float*)d_in[20];
    const float* W0_ba = (const float*)d_in[21]; const float* b0_ba = (const float*)d_in[22];
    const float* W1_ba = (const float*)d_in[23]; const float* b1_ba = (const float*)d_in[24];
    const float* W0_bb = (const float*)d_in[25]; const float* b0_bb = (const float*)d_in[26];
    const float* W1_bb = (const float*)d_in[27]; const float* b1_bb = (const float*)d_in[28];
    const float* att0_a_W1 = (const float*)d_in[29];
    const float* att0_a_b1 = (const float*)d_in[30];
    const float* att0_a_W2 = (const float*)d_in[31];
    const float* att1_a_W1 = (const float*)d_in[32];
    const float* att1_a_b1 = (const float*)d_in[33];
    const float* att1_a_W2 = (const float*)d_in[34];
    const float* Wf_a = (const float*)d_in[35]; const float* bf_a = (const float*)d_in[36];
    const float* att0_b_W1 = (const float*)d_in[37];
    const float* att0_b_b1 = (const float*)d_in[38];
    const float* att0_b_W2 = (const float*)d_in[39];
    const float* att1_b_W1 = (const float*)d_in[40];
    const float* att1_b_b1 = (const float*)d_in[41];
    const float* att1_b_W2 = (const float*)d_in[42];
    const float* Wf_b = (const float*)d_in[43]; const float* bf_b = (const float*)d_in[44];

    const int E_r[4] = { in_sizes[1], in_sizes[4], in_sizes[7], in_sizes[10] };
    const int* rows_r[4] = { row_aa, row_ab, row_ba, row_bb };
    const int* cols_r[4] = { col_aa, col_ab, col_ba, col_bb };
    const float* vals_r[4] = { val_aa, val_ab, val_ba, val_bb };

    const size_t RSZ = (size_t)12800000;
    size_t Etot = (size_t)E_r[0] + E_r[1] + E_r[2] + E_r[3];
    size_t need = (3 * RSZ + (size_t)4 * (NROW + 1) + (size_t)4 * NBUK
                   + (size_t)4 * (NBUK + 1) + 2 * Etot + 66624 + 64) * 4;
    if (ws_size < need) return;

    float* ws = (float*)d_ws;
    float* A0 = ws;
    float* A1 = ws + RSZ;
    float* A2 = ws + 2 * RSZ;
    float* A3 = (float*)d_out;            // e1_b lives here until final projection
    int*   rp4    = (int*)(ws + 3 * RSZ);
    int*   gcur4  = rp4 + (size_t)4 * (NROW + 1);
    int*   gbase4 = gcur4 + (size_t)4 * NBUK;
    int2*  edgesS = (int2*)(gbase4 + (size_t)4 * (NBUK + 1));
    __half* wtH   = (__half*)((int*)edgesS + 2 * Etot);   // 133120 halves, 16B-aligned
    int2*  stag   = (int2*)ws;            // staging overlaps A0/A1 (unused during build)

    size_t eoff[4];
    eoff[0] = 0; eoff[1] = eoff[0] + E_r[0];
    eoff[2] = eoff[1] + E_r[1]; eoff[3] = eoff[2] + E_r[2];

    float* out = (float*)d_out;
    const float* fa = feat;
    const float* fb = feat + (size_t)NA * FT;

    const dim3 blk(256);
    const int gM128 = (NROW + 127) / 128;      // mgemm BN=128 grid
    const int gM256 = (NROW + 255) / 256;      // mgemm BN=64 grid
    const int spg128 = ((NROW + 3) / 4 * 64 + 255) / 256;   // spmm F=128: 4 rows/wave
    const int spg64  = ((NROW + 7) / 8 * 64 + 255) / 256;   // spmm F=64:  8 rows/wave
    const int ag  = (NROW + 31) / 32;          // att2 NT=32

    // fp16 col-major weight offsets (halves)
    const int o0aa = 0,      o0ab = 16384, o0ba = 32768, o0bb = 49152;
    const int o1aa = 65536,  o1ab = 73728, o1ba = 81920, o1bb = 90112;
    const int ofau = 98304,  ofaf = 102400, ofbu = 110592, ofbf = 114688;
    const int oA0a = 122880, oA0b = 126976, oA1a = 131072, oA1b = 132096;

    // ================= weight conversion + CSR build =================
    zero_k<<<(NBUK + 255) / 256, blk, 0, stream>>>((float4*)gcur4, NBUK);  // 4*NBUK ints
    {
        WJobs jb;
        jb.j[0]  = { W0_aa, 128, 128, o0aa };
        jb.j[1]  = { W0_ab, 128, 128, o0ab };
        jb.j[2]  = { W0_ba, 128, 128, o0ba };
        jb.j[3]  = { W0_bb, 128, 128, o0bb };
        jb.j[4]  = { W1_aa, 128, 64,  o1aa };
        jb.j[5]  = { W1_ab, 128, 64,  o1ab };
        jb.j[6]  = { W1_ba, 128, 64,  o1ba };
        jb.j[7]  = { W1_bb, 128, 64,  o1bb };
        jb.j[8]  = { Wf_a,            64,  64, ofau };
        jb.j[9]  = { Wf_a + 64 * 64,  128, 64, ofaf };
        jb.j[10] = { Wf_b,            64,  64, ofbu };
        jb.j[11] = { Wf_b + 64 * 64,  128, 64, ofbf };
        jb.j[12] = { att0_a_W1, 128, 32, oA0a };
        jb.j[13] = { att0_b_W1, 128, 32, oA0b };
        jb.j[14] = { att1_a_W1, 64,  16, oA1a };
        jb.j[15] = { att1_b_W1, 64,  16, oA1b };
        cvtw_k<<<16, blk, 0, stream>>>(jb, wtH);
    }
    for (int r = 0; r < 4; r++)
        binA_k<<<(E_r[r] + CHUNK - 1) / CHUNK, blk, 0, stream>>>(
            rows_r[r], cols_r[r], vals_r[r], gcur4 + (size_t)r * NBUK,
            stag + (size_t)r * NBUK * BCAP, E_r[r]);
    scanb_k<<<4, blk, 0, stream>>>(gcur4, gbase4, rp4);
    for (int r = 0; r < 4; r++)
        placeB_k<<<NBUK, blk, 0, stream>>>(
            gcur4 + (size_t)r * NBUK, gbase4 + (size_t)r * (NBUK + 1),
            stag + (size_t)r * NBUK * BCAP, edgesS + eoff[r],
            rp4 + (size_t)r * (NROW + 1), NROW);

    const int* rp_aa = rp4;
    const int* rp_ab = rp4 + (NROW + 1);
    const int* rp_ba = rp4 + 2 * (NROW + 1);
    const int* rp_bb = rp4 + 3 * (NROW + 1);
    const int2* es_aa = edgesS + eoff[0];
    const int2* es_ab = edgesS + eoff[1];
    const int2* es_ba = edgesS + eoff[2];
    const int2* es_bb = edgesS + eoff[3];

    const __half* H0 = (const __half*)A0;   // fp16 view of the pre-agg buffer

    // ================= layer 0, type a =================
    mgemm_k<128, 128, false, false, true><<<gM128, blk, 0, stream>>>(fa, wtH + o0aa, nullptr, A0, NA);
    spmm_csr_k<128><<<spg128, blk, 0, stream>>>(rp_aa, es_aa, H0, b0_aa, A1, NA);
    mgemm_k<128, 128, false, false, true><<<gM128, blk, 0, stream>>>(fb, wtH + o0ab, nullptr, A0, NB);
    spmm_csr_k<128><<<spg128, blk, 0, stream>>>(rp_ab, es_ab, H0, b0_ab, A2, NA);
    att2_k<128, 32><<<ag, blk, 0, stream>>>(A1, A2, wtH + oA0a, att0_a_b1, att0_a_W2, A1, NA);
    // e1_a in A1

    // ================= layer 0, type b =================
    mgemm_k<128, 128, false, false, true><<<gM128, blk, 0, stream>>>(fa, wtH + o0ba, nullptr, A0, NA);
    spmm_csr_k<128><<<spg128, blk, 0, stream>>>(rp_ba, es_ba, H0, b0_ba, A3, NB);
    mgemm_k<128, 128, false, false, true><<<gM128, blk, 0, stream>>>(fb, wtH + o0bb, nullptr, A0, NB);
    spmm_csr_k<128><<<spg128, blk, 0, stream>>>(rp_bb, es_bb, H0, b0_bb, A2, NB);
    att2_k<128, 32><<<ag, blk, 0, stream>>>(A3, A2, wtH + oA0b, att0_b_b1, att0_b_W2, A3, NB);
    // e1_b in A3 (= d_out region)

    float* A0lo = A0;            float* A0hi = A0 + RSZ / 2;
    float* A2lo = A2;            float* A2hi = A2 + RSZ / 2;
    const __half* H0lo = (const __half*)A0lo;
    const __half* H2lo = (const __half*)A2lo;

    // ================= layer 1, type a =================
    mgemm_k<128, 64, false, false, true><<<gM256, blk, 0, stream>>>(A1, wtH + o1aa, nullptr, A0lo, NA);
    spmm_csr_k<64><<<spg64, blk, 0, stream>>>(rp_aa, es_aa, H0lo, b1_aa, A0hi, NA);
    mgemm_k<128, 64, false, false, true><<<gM256, blk, 0, stream>>>(A3, wtH + o1ab, nullptr, A2lo, NB);
    spmm_csr_k<64><<<spg64, blk, 0, stream>>>(rp_ab, es_ab, H2lo, b1_ab, A2hi, NA);
    att2_k<64, 16><<<ag, blk, 0, stream>>>(A0hi, A2hi, wtH + oA1a, att1_a_b1, att1_a_W2, A0hi, NA);
    // u_a in A0hi

    // ================= layer 1, type b =================
    mgemm_k<128, 64, false, false, true><<<gM256, blk, 0, stream>>>(A1, wtH + o1ba, nullptr, A2lo, NA);
    spmm_csr_k<64><<<spg64, blk, 0, stream>>>(rp_ba, es_ba, H2lo, b1_ba, A2hi, NB);
    mgemm_k<128, 64, false, false, true><<<gM256, blk, 0, stream>>>(A3, wtH + o1bb, nullptr, A2lo, NB);
    spmm_csr_k<64><<<spg64, blk, 0, stream>>>(rp_bb, es_bb, H2lo, b1_bb, A0lo, NB);
    att2_k<64, 16><<<ag, blk, 0, stream>>>(A2hi, A0lo, wtH + oA1b, att1_b_b1, att1_b_W2, A2hi, NB);
    // u_b in A2hi

    // ================= final projection =================
    mgemm_k<64,  64, true,  false, false><<<gM256, blk, 0, stream>>>(A0hi, wtH + ofau, bf_a, out, NA);
    mgemm_k<128, 64, false, true,  false><<<gM256, blk, 0, stream>>>(fa, wtH + ofaf, nullptr, out, NA);
    mgemm_k<64,  64, true,  false, false><<<gM256, blk, 0, stream>>>(A2hi, wtH + ofbu, bf_b, out + (size_t)NA * OUTD, NB);
    mgemm_k<128, 64, false, true,  false><<<gM256, blk, 0, stream>>>(fb, wtH + ofbf, nullptr, out + (size_t)NA * OUTD, NB);
}